// Round 3
// baseline (163.632 us; speedup 1.0000x reference)
//
#include <hip/hip_runtime.h>
#include <hip/hip_cooperative_groups.h>

// Rydberg Hamiltonian apply: out[k] = diag(k)*state[k] + sum_b c_b * state[k ^ (1<<b)]
// N_QUBITS=22, DIM=2^22. Element bit b <-> qubit (21-b). c_b = 0.5*rabi[21-b].
// Single cooperative kernel, three phases:
//   P0 (blocks 0..3): build diag tables dlo/dhi/C            (consumed only after grid sync)
//   P1 (all blocks):  out  = sum_{b=13..21} c_b*state[k^2^b] (hi butterfly, 64KB LDS tile)
//   -- grid.sync() --
//   P2 (all blocks):  out += diag(k)*state[k] + sum_{b=0..12} c_b*state[k^2^b]
// Global traffic ~85 MB total, one launch.

#define NQ 22
#define DIM (1u << NQ)     // 4194304
#define THREADS 512
#define NBLK 256

__device__ __align__(16) float g_dlo[2048];
__device__ __align__(16) float g_dhi[2048];
__device__ float g_C[2048 * 11];

__device__ __forceinline__ int uidx(int i, int j) {
    // np.triu_indices(22, k=1) row-major flatten, i<j
    return i * (43 - i) / 2 + (j - i - 1);
}

__global__ __launch_bounds__(THREADS, 2) void ryd_fused_kernel(
        const float* __restrict__ state, const float* __restrict__ rabi,
        const float* __restrict__ detune, const float* __restrict__ U,
        float* __restrict__ out) {
    __shared__ float4 lds[4096];   // 64 KB, reused across phases
    const float4* __restrict__ sF4 = (const float4*)state;
    float4* __restrict__ oF4 = (float4*)out;
    const unsigned t = threadIdx.x;
    const unsigned blk = blockIdx.x;

    // ---------------- Phase 0: diag tables (global tid < 2048) ----------------
    const unsigned gtid = blk * THREADS + t;
    if (gtid < 2048) {
        const int h = (int)gtid;
        // dlo: lo bit j (element bit j) <-> qubit 21-j
        float s = 0.f;
        for (int j = 0; j < 11; ++j)
            if ((h >> j) & 1) s -= detune[21 - j];
        for (int j2 = 1; j2 < 11; ++j2)
            for (int j1 = 0; j1 < j2; ++j1)
                if (((h >> j1) & 1) && ((h >> j2) & 1))
                    s += U[uidx(21 - j2, 21 - j1)];
        g_dlo[h] = s;
        // dhi: hi bit j (element bit 11+j) <-> qubit 10-j
        float s2 = 0.f;
        for (int j = 0; j < 11; ++j)
            if ((h >> j) & 1) s2 -= detune[10 - j];
        for (int j2 = 1; j2 < 11; ++j2)
            for (int j1 = 0; j1 < j2; ++j1)
                if (((h >> j1) & 1) && ((h >> j2) & 1))
                    s2 += U[uidx(10 - j2, 10 - j1)];
        g_dhi[h] = s2;
        // C[h][j]: hi qubit (10-jh) always < lo qubit (21-j)
        for (int j = 0; j < 11; ++j) {
            float c = 0.f;
            for (int jh = 0; jh < 11; ++jh)
                if ((h >> jh) & 1) c += U[uidx(10 - jh, 21 - j)];
            g_C[h * 11 + j] = c;
        }
    }

    // ---------------- Phase 1: hi butterfly (element bits 13..21) ----------------
    // f4 index F = hi*2048 + base + j4, hi = F>>11 in [0,512). Block owns 8
    // consecutive lo-f4 (128B rows -> fully coalesced global and LDS access).
    {
        float cb[9];
#pragma unroll
        for (int b = 0; b < 9; ++b) cb[b] = 0.5f * rabi[8 - b];  // bit 13+b <-> qubit 8-b
        const unsigned j4 = t & 7u;
        const unsigned hrow = t >> 3;          // [0,64)
        const unsigned base = blk * 8u;        // 256 blocks x 8 = 2048 lo-f4
#pragma unroll
        for (int m = 0; m < 8; ++m) {
            const unsigned hi = hrow + 64u * (unsigned)m;
            lds[hi * 8u + j4] = sF4[hi * 2048u + base + j4];
        }
        __syncthreads();
#pragma unroll
        for (int m = 0; m < 8; ++m) {
            const unsigned hi = hrow + 64u * (unsigned)m;
            float4 acc = {0.f, 0.f, 0.f, 0.f};
#pragma unroll
            for (int b = 0; b < 9; ++b) {
                const float4 p = lds[(hi ^ (1u << b)) * 8u + j4];
                acc.x += cb[b] * p.x; acc.y += cb[b] * p.y;
                acc.z += cb[b] * p.z; acc.w += cb[b] * p.w;
            }
            oF4[hi * 2048u + base + j4] = acc;
        }
    }

    // ---------------- grid-wide barrier (device-scope coherence) ----------------
    __threadfence();
    cooperative_groups::this_grid().sync();
    __threadfence();
    __syncthreads();

    // ---------------- Phase 2: diag + lo butterfly (element bits 0..12) ----------------
    {
        float4* tileS = lds;                       // 2048 f4 = 32 KB
        float4* dloS4 = lds + 2048;                // 512 f4 = 8 KB (dlo table)
        dloS4[t & 511u] = ((const float4*)g_dlo)[t & 511u];
        const float r0 = 0.5f * rabi[21];
        const float r1 = 0.5f * rabi[20];
#pragma unroll
        for (unsigned i = 0; i < 2; ++i) {
            const unsigned T = blk * 2u + i;       // tile id in [0,512)
            __syncthreads();                       // previous readers done
            float4 vreg[4];
#pragma unroll
            for (int c = 0; c < 4; ++c) {
                const unsigned f = t + 512u * (unsigned)c;
                vreg[c] = sF4[T * 2048u + f];
                tileS[f] = vreg[c];
            }
            __syncthreads();
            const unsigned tileHi = T * 4u;
#pragma unroll
            for (int c = 0; c < 4; ++c) {
                const unsigned f = t + 512u * (unsigned)c;   // f>>9 == c
                const unsigned F = T * 2048u + f;
                const float4 prev = oF4[F];                  // phase-1 partial
                const unsigned hi = tileHi + (unsigned)c;    // block-uniform
                float cj[11];
#pragma unroll
                for (int j = 0; j < 11; ++j) cj[j] = g_C[hi * 11u + j];
                float s = g_dhi[hi];
                const unsigned m = f & 511u;                 // element bits 2..10
#pragma unroll
                for (int j = 0; j < 9; ++j)
                    s += ((m >> j) & 1u) ? cj[j + 2] : 0.0f;
                const float4 dl = dloS4[m];
                const float4 v = vreg[c];
                const float d0 = s + dl.x;
                const float d1 = s + cj[0] + dl.y;
                const float d2 = s + cj[1] + dl.z;
                const float d3 = s + cj[0] + cj[1] + dl.w;
                float4 acc;
                acc.x = d0 * v.x; acc.y = d1 * v.y;
                acc.z = d2 * v.z; acc.w = d3 * v.w;
                // element bit 0 (qubit 21): swap within float pairs
                acc.x += r0 * v.y; acc.y += r0 * v.x;
                acc.z += r0 * v.w; acc.w += r0 * v.z;
                // element bit 1 (qubit 20): swap halves of the float4
                acc.x += r1 * v.z; acc.y += r1 * v.w;
                acc.z += r1 * v.x; acc.w += r1 * v.y;
                // element bits 2..12: partner float4 in LDS
#pragma unroll
                for (int b = 2; b <= 12; ++b) {
                    const float rb = 0.5f * rabi[21 - b];
                    const float4 p = tileS[f ^ (1u << (b - 2))];
                    acc.x += rb * p.x; acc.y += rb * p.y;
                    acc.z += rb * p.z; acc.w += rb * p.w;
                }
                acc.x += prev.x; acc.y += prev.y;
                acc.z += prev.z; acc.w += prev.w;
                oF4[F] = acc;
            }
        }
    }
}

extern "C" void kernel_launch(void* const* d_in, const int* in_sizes, int n_in,
                              void* d_out, int out_size, void* d_ws, size_t ws_size,
                              hipStream_t stream) {
    const float* state  = (const float*)d_in[0];
    const float* rabi   = (const float*)d_in[1];
    const float* detune = (const float*)d_in[2];
    const float* U      = (const float*)d_in[3];
    float* out = (float*)d_out;
    (void)in_sizes; (void)n_in; (void)out_size; (void)d_ws; (void)ws_size;

    void* args[] = {(void*)&state, (void*)&rabi, (void*)&detune, (void*)&U, (void*)&out};
    hipLaunchCooperativeKernel((const void*)ryd_fused_kernel, dim3(NBLK), dim3(THREADS),
                               args, 0, stream);
}

// Round 4
// 25.583 us; speedup vs baseline: 6.3961x; 6.3961x over previous
//
#include <hip/hip_runtime.h>

// Rydberg Hamiltonian apply: out[k] = diag(k)*state[k] + sum_b c_b * state[k ^ (1<<b)]
// N_QUBITS=22, DIM=2^22. Element bit b <-> qubit (21-b). c_b = 0.5*rabi[21-b].
//
// SINGLE ordinary kernel (512 blocks x 512 threads), one sweep:
//  - per-block LDS preamble builds all diag tables (no separate table kernel):
//      dloS[2048]  : detune + pairwise terms over element bits 0..10
//      CJ[4][11]   : cross terms hi11=(tile*4+c) -> lo bit j
//      S4[4]       : detune + pairwise within hi11
//  - bits 0..1  : register permutes of own float4
//  - bits 2..12 : partners from 32 KB LDS tile
//  - bits 13..21: partners from global; XCD-aware tile swizzle makes the 6
//    low partner tiles same-XCD (L2-hit), rest L3. HBM ~= compulsory 16R+16W.

#define THREADS 512
#define NBLK 512

__device__ __forceinline__ int uidx(int i, int j) {
    // np.triu_indices(22, k=1) row-major flatten, i<j
    return i * (43 - i) / 2 + (j - i - 1);
}

__global__ __launch_bounds__(THREADS, 2) void ryd_kernel(
        const float* __restrict__ state, const float* __restrict__ rabi,
        const float* __restrict__ detune, const float* __restrict__ U,
        float* __restrict__ out) {
    __shared__ float4 tileS[2048];   // 32 KB state tile (element bits 0..12)
    __shared__ float  dloS[2048];    // 8 KB diag table over element bits 0..10
    __shared__ float  Us[231];
    __shared__ float  dets[22];
    __shared__ float  CJ[4][11];
    __shared__ float  S4[4];

    const float4* __restrict__ sF4 = (const float4*)state;
    float4* __restrict__ oF4 = (float4*)out;
    const unsigned t = threadIdx.x;
    const unsigned blk = blockIdx.x;
    // XCD-locality swizzle: blocks with equal (blk&7) land on one XCD and own
    // a contiguous 64-tile group; partner tiles tile^2^j, j<6 stay in-group.
    const unsigned tile = ((blk & 7u) << 6) | (blk >> 3);   // [0,512)

    // ---- stage U, detune into LDS ----
    if (t < 231u) Us[t] = U[t];
    else if (t < 253u) dets[t - 231u] = detune[t - 231u];
    __syncthreads();

    // ---- dlo table: element bits 0..10 (bit j <-> qubit 21-j) ----
#pragma unroll
    for (int r = 0; r < 4; ++r) {
        const unsigned m = t + 512u * (unsigned)r;
        float s = 0.f;
        for (int j2 = 0; j2 < 11; ++j2) {
            if ((m >> j2) & 1u) {
                s -= dets[21 - j2];
                for (int j1 = 0; j1 < j2; ++j1)
                    if ((m >> j1) & 1u) s += Us[uidx(21 - j2, 21 - j1)];
            }
        }
        dloS[m] = s;
    }
    // ---- per-block hi tables: hi11 = (tile<<2)|c, bit jh <-> qubit 10-jh ----
    if (t < 44u) {
        const int c = (int)t / 11, j = (int)t % 11;
        const unsigned h = (tile << 2) | (unsigned)c;
        float cc = 0.f;
        for (int jh = 0; jh < 11; ++jh)
            if ((h >> jh) & 1u) cc += Us[uidx(10 - jh, 21 - j)];
        CJ[c][j] = cc;
    } else if (t < 48u) {
        const int c = (int)t - 44;
        const unsigned h = (tile << 2) | (unsigned)c;
        float s = 0.f;
        for (int j2 = 0; j2 < 11; ++j2) {
            if ((h >> j2) & 1u) {
                s -= dets[10 - j2];
                for (int j1 = 0; j1 < j2; ++j1)
                    if ((h >> j1) & 1u) s += Us[uidx(10 - j2, 10 - j1)];
            }
        }
        S4[c] = s;
    }

    // ---- load own state tile (overlaps with table math above) ----
    float4 vreg[4];
#pragma unroll
    for (int c = 0; c < 4; ++c) {
        const unsigned f = t + 512u * (unsigned)c;
        vreg[c] = sF4[tile * 2048u + f];
        tileS[f] = vreg[c];
    }
    __syncthreads();   // tables + tile ready

    const float r0 = 0.5f * rabi[21];
    const float r1 = 0.5f * rabi[20];
    float cb[9];
#pragma unroll
    for (int b = 0; b < 9; ++b) cb[b] = 0.5f * rabi[8 - b];  // bit 13+b <-> qubit 8-b

#pragma unroll
    for (int c = 0; c < 4; ++c) {
        const unsigned f = t + 512u * (unsigned)c;   // f bits 9..10 == c
        const unsigned F = tile * 2048u + f;
        // far partners (element bits 13..21): issue all 9 loads early
        float4 pg[9];
#pragma unroll
        for (int b = 0; b < 9; ++b)
            pg[b] = sF4[F ^ (2048u << b)];

        float cj[11];
#pragma unroll
        for (int j = 0; j < 11; ++j) cj[j] = CJ[c][j];
        float s = S4[c];
        const unsigned m = f & 511u;                 // element bits 2..10
#pragma unroll
        for (int j = 0; j < 9; ++j)
            s += ((m >> j) & 1u) ? cj[j + 2] : 0.f;
        const float4 dl = ((const float4*)dloS)[m];  // element bits 0..1 in comps
        const float4 v = vreg[c];
        const float d0 = s + dl.x;
        const float d1 = s + cj[0] + dl.y;
        const float d2 = s + cj[1] + dl.z;
        const float d3 = s + cj[0] + cj[1] + dl.w;
        float4 acc;
        acc.x = d0 * v.x; acc.y = d1 * v.y; acc.z = d2 * v.z; acc.w = d3 * v.w;
        // element bit 0 (qubit 21): swap within float pairs
        acc.x += r0 * v.y; acc.y += r0 * v.x; acc.z += r0 * v.w; acc.w += r0 * v.z;
        // element bit 1 (qubit 20): swap halves of the float4
        acc.x += r1 * v.z; acc.y += r1 * v.w; acc.z += r1 * v.x; acc.w += r1 * v.y;
        // element bits 2..12: partner float4 in LDS
#pragma unroll
        for (int b = 2; b <= 12; ++b) {
            const float rb = 0.5f * rabi[21 - b];
            const float4 p = tileS[f ^ (1u << (b - 2))];
            acc.x += rb * p.x; acc.y += rb * p.y; acc.z += rb * p.z; acc.w += rb * p.w;
        }
        // element bits 13..21: the prefetched far partners
#pragma unroll
        for (int b = 0; b < 9; ++b) {
            acc.x += cb[b] * pg[b].x; acc.y += cb[b] * pg[b].y;
            acc.z += cb[b] * pg[b].z; acc.w += cb[b] * pg[b].w;
        }
        oF4[F] = acc;
    }
}

extern "C" void kernel_launch(void* const* d_in, const int* in_sizes, int n_in,
                              void* d_out, int out_size, void* d_ws, size_t ws_size,
                              hipStream_t stream) {
    const float* state  = (const float*)d_in[0];
    const float* rabi   = (const float*)d_in[1];
    const float* detune = (const float*)d_in[2];
    const float* U      = (const float*)d_in[3];
    float* out = (float*)d_out;
    (void)in_sizes; (void)n_in; (void)out_size; (void)d_ws; (void)ws_size;

    hipLaunchKernelGGL(ryd_kernel, dim3(NBLK), dim3(THREADS), 0, stream,
                       state, rabi, detune, U, out);
}

// Round 5
// 20.917 us; speedup vs baseline: 7.8229x; 1.2231x over previous
//
#include <hip/hip_runtime.h>

// Rydberg Hamiltonian apply: out[k] = diag(k)*state[k] + sum_b c_b * state[k ^ (1<<b)]
// N_QUBITS=22, DIM=2^22. Element bit b <-> qubit (21-b). c_b = 0.5*rabi[21-b].
//
// Single kernel, 512 blocks x 512 threads, 2 blocks/CU (VGPR capped at 128):
//  - bits 0..1  : register permutes of own float4
//  - bits 2..12 : partners from 32 KB LDS tile
//  - bits 13..18: same-XCD partner tiles (L2) loaded in-chunk
//  - bits 19..21: cross-XCD partners (L3) prefetched ONE CHUNK AHEAD (ping-pong regs)
//  - diag via per-block tables; dlo built with 9-bit base + analytic bit-9/10 extension
//  - out stored non-temporally (write-once; don't evict partner tiles from L2)

#define THREADS 512
#define NBLK 512

typedef float fvec4 __attribute__((ext_vector_type(4)));

__device__ __forceinline__ int uidx(int i, int j) {
    // np.triu_indices(22, k=1) row-major flatten, i<j
    return i * (43 - i) / 2 + (j - i - 1);
}

__global__ __launch_bounds__(THREADS, 4) void ryd_kernel(
        const float* __restrict__ state, const float* __restrict__ rabi,
        const float* __restrict__ detune, const float* __restrict__ U,
        float* __restrict__ out) {
    __shared__ float4 tileS[2048];               // 32 KB state tile (element bits 0..12)
    __shared__ __align__(16) float dloS[2048];   // 8 KB diag table over element bits 0..10
    __shared__ float Us[231];
    __shared__ float dets[22];
    __shared__ float CJ[4][11];
    __shared__ float S4v[4];

    const float4* __restrict__ sF4 = (const float4*)state;
    float4* __restrict__ oF4 = (float4*)out;
    const unsigned t = threadIdx.x;
    const unsigned blk = blockIdx.x;
    // XCD-locality swizzle: the 64 co-resident blocks of one XCD own a
    // contiguous 64-tile group; partner tiles tile^2^j, j<6 stay in-group (L2).
    const unsigned tile = ((blk & 7u) << 6) | (blk >> 3);   // [0,512)
    const unsigned tbase = tile * 2048u;

    // ---- stage U, detune into LDS ----
    if (t < 231u) Us[t] = U[t];
    else if (t < 253u) dets[t - 231u] = detune[t - 231u];

    // ---- issue own-tile loads + chunk-0's L3 partner loads BEFORE table math ----
    float4 vreg[4];
#pragma unroll
    for (int c = 0; c < 4; ++c)
        vreg[c] = sF4[tbase + t + 512u * (unsigned)c];
    float4 pgl[2][3];   // ping-pong prefetch for element bits 19..21 (b = 6..8)
#pragma unroll
    for (int b = 6; b < 9; ++b)
        pgl[0][b - 6] = sF4[(tbase + t) ^ (2048u << b)];

    __syncthreads();    // Us/dets visible

    // ---- dlo table over element bits 0..10 (bit j <-> qubit 21-j) ----
    // base over bits 0..8 (= t), analytic extension for bits 9,10.
    {
        float base = 0.f, R9 = 0.f, R10 = 0.f;
#pragma unroll
        for (int j2 = 0; j2 < 9; ++j2) {
            if ((t >> j2) & 1u) {
                base -= dets[21 - j2];
#pragma unroll
                for (int j1 = 0; j1 < j2; ++j1)
                    if ((t >> j1) & 1u) base += Us[uidx(21 - j2, 21 - j1)];
                R9  += Us[uidx(12, 21 - j2)];   // pair (qubit 12, qubit 21-j2)
                R10 += Us[uidx(11, 21 - j2)];   // pair (qubit 11, qubit 21-j2)
            }
        }
        const float w9  = -dets[12];            // bit 9  <-> qubit 12
        const float w10 = -dets[11];            // bit 10 <-> qubit 11
        const float u910 = Us[uidx(11, 12)];
        dloS[t]         = base;
        dloS[t + 512u]  = base + w9 + R9;
        dloS[t + 1024u] = base + w10 + R10;
        dloS[t + 1536u] = base + w9 + R9 + w10 + R10 + u910;
    }
    // ---- per-block hi tables: hi11 = (tile<<2)|c, bit jh <-> qubit 10-jh ----
    if (t < 44u) {
        const int c = (int)t / 11, j = (int)t % 11;
        const unsigned h = (tile << 2) | (unsigned)c;
        float cc = 0.f;
        for (int jh = 0; jh < 11; ++jh)
            if ((h >> jh) & 1u) cc += Us[uidx(10 - jh, 21 - j)];
        CJ[c][j] = cc;
    } else if (t < 48u) {
        const int c = (int)t - 44;
        const unsigned h = (tile << 2) | (unsigned)c;
        float s = 0.f;
        for (int j2 = 0; j2 < 11; ++j2) {
            if ((h >> j2) & 1u) {
                s -= dets[10 - j2];
                for (int j1 = 0; j1 < j2; ++j1)
                    if ((h >> j1) & 1u) s += Us[uidx(10 - j2, 10 - j1)];
            }
        }
        S4v[c] = s;
    }

    // ---- commit own tile to LDS ----
#pragma unroll
    for (int c = 0; c < 4; ++c)
        tileS[t + 512u * (unsigned)c] = vreg[c];
    __syncthreads();   // tables + tile ready

    const float r0 = 0.5f * rabi[21];
    const float r1 = 0.5f * rabi[20];
    float cb[9];
#pragma unroll
    for (int b = 0; b < 9; ++b) cb[b] = 0.5f * rabi[8 - b];  // bit 13+b <-> qubit 8-b

#pragma unroll
    for (int c = 0; c < 4; ++c) {
        const unsigned f = t + 512u * (unsigned)c;   // f bits 9..10 == c
        const unsigned F = tbase + f;
        // prefetch NEXT chunk's cross-XCD (L3) partners
        if (c < 3) {
#pragma unroll
            for (int b = 6; b < 9; ++b)
                pgl[(c + 1) & 1][b - 6] = sF4[(F + 512u) ^ (2048u << b)];
        }
        // in-chunk same-XCD (L2) partners, element bits 13..18
        float4 pg[6];
#pragma unroll
        for (int b = 0; b < 6; ++b)
            pg[b] = sF4[F ^ (2048u << b)];

        float cj[11];
#pragma unroll
        for (int j = 0; j < 11; ++j) cj[j] = CJ[c][j];
        float s = S4v[c];
        const unsigned m = f & 511u;                 // element bits 2..10
#pragma unroll
        for (int j = 0; j < 9; ++j)
            s += ((m >> j) & 1u) ? cj[j + 2] : 0.f;
        const float4 dl = ((const float4*)dloS)[m];  // element bits 0..1 in comps
        const float4 v = vreg[c];
        const float d0 = s + dl.x;
        const float d1 = s + cj[0] + dl.y;
        const float d2 = s + cj[1] + dl.z;
        const float d3 = s + cj[0] + cj[1] + dl.w;
        float4 acc;
        acc.x = d0 * v.x; acc.y = d1 * v.y; acc.z = d2 * v.z; acc.w = d3 * v.w;
        // element bit 0 (qubit 21): swap within float pairs
        acc.x += r0 * v.y; acc.y += r0 * v.x; acc.z += r0 * v.w; acc.w += r0 * v.z;
        // element bit 1 (qubit 20): swap halves of the float4
        acc.x += r1 * v.z; acc.y += r1 * v.w; acc.z += r1 * v.x; acc.w += r1 * v.y;
        // element bits 2..12: partner float4 in LDS
#pragma unroll
        for (int b = 2; b <= 12; ++b) {
            const float rb = 0.5f * rabi[21 - b];
            const float4 p = tileS[f ^ (1u << (b - 2))];
            acc.x += rb * p.x; acc.y += rb * p.y; acc.z += rb * p.z; acc.w += rb * p.w;
        }
        // element bits 13..18: in-chunk L2 partners
#pragma unroll
        for (int b = 0; b < 6; ++b) {
            acc.x += cb[b] * pg[b].x; acc.y += cb[b] * pg[b].y;
            acc.z += cb[b] * pg[b].z; acc.w += cb[b] * pg[b].w;
        }
        // element bits 19..21: prefetched L3 partners
#pragma unroll
        for (int q = 0; q < 3; ++q) {
            const float4 p = pgl[c & 1][q];
            acc.x += cb[6 + q] * p.x; acc.y += cb[6 + q] * p.y;
            acc.z += cb[6 + q] * p.z; acc.w += cb[6 + q] * p.w;
        }
        // write-once output: non-temporal, keep L2 for partner tiles
        union { float4 s4; fvec4 v4; } u;
        u.s4 = acc;
        __builtin_nontemporal_store(u.v4, reinterpret_cast<fvec4*>(oF4 + F));
    }
}

extern "C" void kernel_launch(void* const* d_in, const int* in_sizes, int n_in,
                              void* d_out, int out_size, void* d_ws, size_t ws_size,
                              hipStream_t stream) {
    const float* state  = (const float*)d_in[0];
    const float* rabi   = (const float*)d_in[1];
    const float* detune = (const float*)d_in[2];
    const float* U      = (const float*)d_in[3];
    float* out = (float*)d_out;
    (void)in_sizes; (void)n_in; (void)out_size; (void)d_ws; (void)ws_size;

    hipLaunchKernelGGL(ryd_kernel, dim3(NBLK), dim3(THREADS), 0, stream,
                       state, rabi, detune, U, out);
}